// Round 2
// baseline (91.180 us; speedup 1.0000x reference)
//
#include <hip/hip_runtime.h>

static constexpr int K_TOT   = 1048576;
static constexpr int KM1     = K_TOT - 1;   // softmax elements, k in [1, KM1]
static constexpr int M_S     = 32;
static constexpr int J_ITERS = 32;
static constexpr int SPAN    = 64 * J_ITERS; // 2048 elements per wave

__device__ __forceinline__ float fexp2(float x) {
    float r; asm volatile("v_exp_f32 %0, %1" : "=v"(r) : "v"(x)); return r;
}
__device__ __forceinline__ float flog2(float x) {
    float r; asm volatile("v_log_f32 %0, %1" : "=v"(r) : "v"(x)); return r;
}

__global__ void zero_out_kernel(float* out) { out[0] = 0.0f; }

__global__ __launch_bounds__(256) void terp_kernel(
    const float* __restrict__ x,
    const float* __restrict__ ms,
    const float* __restrict__ u,
    float* __restrict__ out,
    int nchunks)
{
    const int lane = threadIdx.x & 63;
    const int wave = threadIdx.x >> 6;
    const int m    = blockIdx.x & 31;   // m fastest -> 32 blocks share same ms chunk
    const int cg   = blockIdx.x >> 5;
    const int chunk = cg * 4 + wave;

    const float x0 = x[0];
    const float x1 = x[1];
    constexpr float TEMP = 2.5f * 0.9999f;
    constexpr float LN2  = 0.69314718055994530942f;
    const float invT = 1.0f / TEMP;
    const float c_ms = invT / LN2;

    float acc = 0.0f;  // accumulated in log2 units

    if (chunk < nchunks) {
        const int k0 = 1 + chunk * SPAN;
        // u2[k] = u[m][k-1][:], ms2[k] = ms[k-1][:]
        const float2* __restrict__ u2  = (const float2*)u + ((size_t)m * KM1 - 1);
        const float2* __restrict__ ms2 = (const float2*)ms - 1;

        float pend_t = 0.0f;
        bool  pend_v = false;   // only ever true on lane 63

        #pragma unroll 4
        for (int j = 0; j < J_ITERS; ++j) {
            const int k = k0 + j * 64 + lane;
            const bool valid = (k <= KM1);
            float t = 0.0f;
            if (valid) {
                const float2 up = u2[k];
                const float2 mp = ms2[k];
                // lu = -log2(u) > 0 ; ln(L0/L1) = ln2*(log2 lu0 - log2 lu1)
                const float lu0 = -flog2(up.x);
                const float lu1 = -flog2(up.y);
                const float a   = flog2(lu0) - flog2(lu1);
                // t = exp2( (ms1-ms0)/(T*ln2) + a/T )
                const float e = fmaf(c_ms, mp.y - mp.x, invT * a);
                t = fexp2(e);
                acc -= 2.0f * flog2(1.0f + t);
                if (k == 1)   acc += flog2(fmaf(x1, t, x0));  // x . mus_1 numerator
                if (k == KM1) acc += flog2(fmaf(x1, t, x0));  // mus_{K-1} . x numerator
            }
            // lane63's deferred coupling with lane0's t of THIS iteration
            const float t0 = __shfl(t, 0);
            if (pend_v) acc += flog2(fmaf(pend_t, t0, 1.0f));
            // intra-iteration coupling: neighbor t from lane+1
            const float tn = __shfl_down(t, 1);
            if (lane < 63 && valid && k < KM1)
                acc += flog2(fmaf(t, tn, 1.0f));
            pend_v = (lane == 63) && valid && (k < KM1);
            pend_t = t;
        }
        // span-boundary coupling: recompute first element of next span
        if (pend_v) {
            const int kn = k0 + SPAN;   // == pend_k + 1, guaranteed <= KM1
            const float2 up = u2[kn];
            const float2 mp = ms2[kn];
            const float lu0 = -flog2(up.x);
            const float lu1 = -flog2(up.y);
            const float a   = flog2(lu0) - flog2(lu1);
            const float e   = fmaf(c_ms, mp.y - mp.x, invT * a);
            const float tnx = fexp2(e);
            acc += flog2(fmaf(pend_t, tnx, 1.0f));
        }
    }

    // wave reduce (64 lanes)
    #pragma unroll
    for (int off = 32; off >= 1; off >>= 1)
        acc += __shfl_down(acc, off);

    __shared__ float ssum[4];
    if (lane == 0) ssum[wave] = acc;
    __syncthreads();
    if (threadIdx.x == 0) {
        const float bs = ssum[0] + ssum[1] + ssum[2] + ssum[3];
        // output = -ln(2) * total_log2_sum / M ; distribute scale per block
        atomicAdd(out, bs * (-LN2 / (float)M_S));
    }
}

extern "C" void kernel_launch(void* const* d_in, const int* in_sizes, int n_in,
                              void* d_out, int out_size, void* d_ws, size_t ws_size,
                              hipStream_t stream) {
    const float* x  = (const float*)d_in[0];
    const float* ms = (const float*)d_in[1];
    const float* u  = (const float*)d_in[2];
    float* out = (float*)d_out;

    zero_out_kernel<<<1, 1, 0, stream>>>(out);

    const int nchunks = (KM1 + SPAN - 1) / SPAN;   // 512
    const int cgs = (nchunks + 3) / 4;             // 128
    dim3 grid(cgs * 32);                           // 4096 blocks, m fastest
    terp_kernel<<<grid, 256, 0, stream>>>(x, ms, u, out, nchunks);
}

// Round 4
// 87.952 us; speedup vs baseline: 1.0367x; 1.0367x over previous
//
#include <hip/hip_runtime.h>

static constexpr int K_TOT   = 1048576;
static constexpr int KM1     = K_TOT - 1;   // softmax elements, k in [1, KM1]
static constexpr int M_S     = 32;
static constexpr int J_ITERS = 32;
static constexpr int SPAN    = 64 * J_ITERS; // 2048 elements per wave

typedef float f32x2 __attribute__((ext_vector_type(2)));

#if __has_builtin(__builtin_amdgcn_logf)
__device__ __forceinline__ float flog2(float x) { return __builtin_amdgcn_logf(x); }
#else
__device__ __forceinline__ float flog2(float x) {
    float r; asm("v_log_f32 %0, %1" : "=v"(r) : "v"(x)); return r;
}
#endif
#if __has_builtin(__builtin_amdgcn_exp2f)
__device__ __forceinline__ float fexp2(float x) { return __builtin_amdgcn_exp2f(x); }
#else
__device__ __forceinline__ float fexp2(float x) {
    float r; asm("v_exp_f32 %0, %1" : "=v"(r) : "v"(x)); return r;
}
#endif

__global__ void zero_out_kernel(float* out) { out[0] = 0.0f; }

// t = exp2( c_ms*(ms1-ms0) + invT*(log2(-log2 u0) - log2(-log2 u1)) )
__device__ __forceinline__ float calc_t(f32x2 up, f32x2 mp, float invT, float c_ms) {
    const float lu0 = -flog2(up.x);
    const float lu1 = -flog2(up.y);
    const float a   = flog2(lu0) - flog2(lu1);
    return fexp2(fmaf(c_ms, mp.y - mp.x, invT * a));
}

__global__ __launch_bounds__(256) void terp_kernel(
    const float* __restrict__ x,
    const float* __restrict__ ms,
    const float* __restrict__ u,
    float* __restrict__ out,
    int nchunks)
{
    const int lane  = threadIdx.x & 63;
    const int wave  = threadIdx.x >> 6;
    const int m     = blockIdx.x & 31;   // m fastest -> 32 blocks share one ms chunk
    const int cg    = blockIdx.x >> 5;
    const int chunk = cg * 4 + wave;

    const float x0 = x[0];
    const float x1 = x[1];
    constexpr float TEMP = 2.5f * 0.9999f;
    constexpr float LN2  = 0.69314718055994530942f;
    const float invT = 1.0f / TEMP;
    const float c_ms = invT / LN2;

    float acc = 0.0f;  // log2 units

    if (chunk < nchunks) {
        const int k0 = 1 + chunk * SPAN;
        // u2[k] = u[m][k-1][:], ms2[k] = ms[k-1][:]
        const f32x2* __restrict__ u2  = (const f32x2*)u + ((size_t)m * KM1 - 1);
        const f32x2* __restrict__ ms2 = (const f32x2*)ms - 1;

        const int kc0 = min(k0 + lane, KM1);
        float t_cur = calc_t(__builtin_nontemporal_load(&u2[kc0]), ms2[kc0], invT, c_ms);

        #pragma unroll 4
        for (int j = 0; j < J_ITERS - 1; ++j) {
            const int k  = k0 + j * 64 + lane;
            const int kn = min(k + 64, KM1);
            const float t_next = calc_t(__builtin_nontemporal_load(&u2[kn]), ms2[kn], invT, c_ms);

            if (k <= KM1) {
                acc -= 2.0f * flog2(1.0f + t_cur);
                if (k == 1)   acc += flog2(fmaf(x1, t_cur, x0));
                if (k == KM1) acc += flog2(fmaf(x1, t_cur, x0));
            }
            // coupling (k, k+1): rotate so lane63 gets t_next[lane 0]
            const float r = (lane == 0) ? t_next : t_cur;
            const float v = __shfl(r, (lane + 1) & 63);
            if (k < KM1) acc += flog2(fmaf(t_cur, v, 1.0f));

            t_cur = t_next;
        }

        // final iteration j = J_ITERS-1: partner for lane63 is next span's first elem
        {
            const int k  = k0 + (J_ITERS - 1) * 64 + lane;
            const int kn = min(k0 + SPAN, KM1);          // uniform across lanes
            const float t_next = calc_t(u2[kn], ms2[kn], invT, c_ms);

            if (k <= KM1) {
                acc -= 2.0f * flog2(1.0f + t_cur);
                if (k == 1)   acc += flog2(fmaf(x1, t_cur, x0));
                if (k == KM1) acc += flog2(fmaf(x1, t_cur, x0));
            }
            const float r = (lane == 0) ? t_next : t_cur;
            const float v = __shfl(r, (lane + 1) & 63);
            if (k < KM1) acc += flog2(fmaf(t_cur, v, 1.0f));
        }
    }

    // wave reduce (64 lanes)
    #pragma unroll
    for (int off = 32; off >= 1; off >>= 1)
        acc += __shfl_down(acc, off);

    __shared__ float ssum[4];
    if (lane == 0) ssum[wave] = acc;
    __syncthreads();
    if (threadIdx.x == 0) {
        const float bs = ssum[0] + ssum[1] + ssum[2] + ssum[3];
        atomicAdd(out, bs * (-LN2 / (float)M_S));
    }
}

extern "C" void kernel_launch(void* const* d_in, const int* in_sizes, int n_in,
                              void* d_out, int out_size, void* d_ws, size_t ws_size,
                              hipStream_t stream) {
    const float* x  = (const float*)d_in[0];
    const float* ms = (const float*)d_in[1];
    const float* u  = (const float*)d_in[2];
    float* out = (float*)d_out;

    zero_out_kernel<<<1, 1, 0, stream>>>(out);

    const int nchunks = (KM1 + SPAN - 1) / SPAN;   // 512
    const int cgs = (nchunks + 3) / 4;             // 128
    dim3 grid(cgs * 32);                           // 4096 blocks, m fastest
    terp_kernel<<<grid, 256, 0, stream>>>(x, ms, u, out, nchunks);
}